// Round 7
// baseline (268.281 us; speedup 1.0000x reference)
//
#include <hip/hip_runtime.h>

// Problem constants (setup_inputs fixed: N=4, Lq=6400, C=256, H=W=80)
#define NB    4
#define LQ    6400
#define CC    256
#define HH    80
#define WW    80
#define HWSZ  (HH*WW)
#define RTOT  (NB*LQ)        // 25600 rows
#define HID   1024

typedef __attribute__((ext_vector_type(8))) short bf16x8;   // 8 bf16 = 4 VGPRs
typedef __attribute__((ext_vector_type(4))) float f32x4;

__device__ __forceinline__ float bf2f(unsigned short u) {
    unsigned int i = ((unsigned int)u) << 16;
    float f; __builtin_memcpy(&f, &i, 4); return f;
}
__device__ __forceinline__ unsigned short f2bf(float f) {
    unsigned int i; __builtin_memcpy(&i, &f, 4);
    unsigned int r = i + 0x7fffu + ((i >> 16) & 1u);   // RNE
    return (unsigned short)(r >> 16);
}

// tanh-form GELU: |err| vs exact-erf gelu ~3e-4 << bf16 quantization of h.
__device__ __forceinline__ float gelu_f(float v) {
    float u = v * (0.7978845608f + 0.0356774081f * (v * v));
    return v / (1.0f + __expf(-2.0f * u));
}

// ---------------- fp32 -> bf16 convert (4 elems/thread) ----------------
__global__ void cvt_k(const float* __restrict__ in, unsigned short* __restrict__ out, int n4) {
    int i = blockIdx.x * 256 + threadIdx.x;
    if (i < n4) {
        float4 u = ((const float4*)in)[i];
        ushort4 o;
        o.x = f2bf(u.x); o.y = f2bf(u.y); o.z = f2bf(u.z); o.w = f2bf(u.w);
        ((ushort4*)out)[i] = o;
    }
}

// ---------------- one-shot weight prep (transpose + fragment swizzles + bias cat) ------
// swizzle layout: group g -> n = g%N, kq = g/N; dst[g*8+j] = bf16(src[(kq*8+j)*N + n])
// — the exact VGPR image an A-fragment wants.
__global__ void prep_k(const float* __restrict__ Wv,   const float* __restrict__ Wout,
                       const float* __restrict__ W1,   const float* __restrict__ W2,
                       const float* __restrict__ Woff, const float* __restrict__ Wa,
                       const float* __restrict__ boff, const float* __restrict__ ba,
                       unsigned short* __restrict__ wtv,  unsigned short* __restrict__ woutS,
                       unsigned short* __restrict__ w1s,  unsigned short* __restrict__ w2s,
                       unsigned short* __restrict__ woas, float* __restrict__ b_oa) {
    int idx = blockIdx.x * 256 + threadIdx.x;
    if (idx < 65536) {                          // wtv transpose: wtv[n*256+k] = Wv[k*256+n]
        int n = idx >> 8, k = idx & 255;
        wtv[idx] = f2bf(Wv[(size_t)k * 256 + n]);
        return;
    }
    idx -= 65536;
    if (idx < 32768) {                          // w1s swizzle (K=256, N=1024)
        int n = idx & 1023, kq = idx >> 10;
        int kb = kq * 8;
        unsigned short* d = w1s + (size_t)idx * 8;
        #pragma unroll
        for (int j = 0; j < 8; ++j) d[j] = f2bf(W1[(size_t)(kb + j) * 1024 + n]);
        return;
    }
    idx -= 32768;
    if (idx < 32768) {                          // w2s swizzle (K=1024, N=256)
        int n = idx & 255, kq = idx >> 8;
        int kb = kq * 8;
        unsigned short* d = w2s + (size_t)idx * 8;
        #pragma unroll
        for (int j = 0; j < 8; ++j) d[j] = f2bf(W2[(size_t)(kb + j) * 256 + n]);
        return;
    }
    idx -= 32768;
    if (idx < 8192) {                           // woutS swizzle (K=256, N=256)
        int n = idx & 255, kq = idx >> 8;
        int kb = kq * 8;
        unsigned short* d = woutS + (size_t)idx * 8;
        #pragma unroll
        for (int j = 0; j < 8; ++j) d[j] = f2bf(Wout[(size_t)(kb + j) * 256 + n]);
        return;
    }
    idx -= 8192;
    if (idx < 4096) {                           // woas swizzle (K=256, Npad=128: Woff|Wa|0)
        int n = idx & 127, kq = idx >> 7;
        int kb = kq * 8;
        unsigned short* d = woas + (size_t)idx * 8;
        #pragma unroll
        for (int j = 0; j < 8; ++j) {
            float v = 0.f;
            if (n < 64)      v = Woff[(size_t)(kb + j) * 64 + n];
            else if (n < 96) v = Wa[(size_t)(kb + j) * 32 + (n - 64)];
            d[j] = f2bf(v);
        }
        return;
    }
    idx -= 4096;
    if (idx < 96) b_oa[idx] = idx < 64 ? boff[idx] : ba[idx - 64];
}

// ---------------- shared LN stage: 64 rows fp32 -> fragment-major bf16 hblob ----------
// 512 threads: 8 threads/row; hblob 32 kq x 1040 B stride (odd 16B-granule -> bank-clean).
__device__ __forceinline__ void ln_stage(const float* __restrict__ xbase,  // + row0*CC
                                         const float* __restrict__ lw,
                                         const float* __restrict__ lb,
                                         unsigned short* hblob, int t) {
    int r = t >> 3, sub = t & 7;
    const float* xr = xbase + (size_t)r * CC;
    float4 xv[4][2];
    float s = 0.f, s2 = 0.f;
    #pragma unroll
    for (int jj = 0; jj < 4; ++jj) {
        #pragma unroll
        for (int u = 0; u < 2; ++u) {
            float4 v = *(const float4*)(xr + sub * 8 + jj * 64 + u * 4);
            xv[jj][u] = v;
            s  += v.x + v.y + v.z + v.w;
            s2 += v.x*v.x + v.y*v.y + v.z*v.z + v.w*v.w;
        }
    }
    #pragma unroll
    for (int m = 1; m < 8; m <<= 1) {
        s  += __shfl_xor(s,  m);
        s2 += __shfl_xor(s2, m);
    }
    float mean = s * (1.0f / CC);
    float var  = s2 * (1.0f / CC) - mean * mean;
    float rstd = rsqrtf(fmaxf(var, 0.0f) + 1e-5f);
    #pragma unroll
    for (int jj = 0; jj < 4; ++jj) {
        int c0 = sub * 8 + jj * 64;
        float4 w0 = *(const float4*)(lw + c0);
        float4 w1 = *(const float4*)(lw + c0 + 4);
        float4 bb0 = *(const float4*)(lb + c0);
        float4 bb1 = *(const float4*)(lb + c0 + 4);
        bf16x8 o;
        o[0] = (short)f2bf((xv[jj][0].x - mean) * rstd * w0.x + bb0.x);
        o[1] = (short)f2bf((xv[jj][0].y - mean) * rstd * w0.y + bb0.y);
        o[2] = (short)f2bf((xv[jj][0].z - mean) * rstd * w0.z + bb0.z);
        o[3] = (short)f2bf((xv[jj][0].w - mean) * rstd * w0.w + bb0.w);
        o[4] = (short)f2bf((xv[jj][1].x - mean) * rstd * w1.x + bb1.x);
        o[5] = (short)f2bf((xv[jj][1].y - mean) * rstd * w1.y + bb1.y);
        o[6] = (short)f2bf((xv[jj][1].z - mean) * rstd * w1.z + bb1.z);
        o[7] = (short)f2bf((xv[jj][1].w - mean) * rstd * w1.w + bb1.w);
        int kq = sub + jj * 8;
        *(bf16x8*)((char*)hblob + kq * 1040 + r * 16) = o;
    }
}

// ---------------- 128x128-tile GEMM (value projection) ----------------
// 256 thr = 4 waves in 2x2 grid; each wave owns 64x64 = 4x4 16x16 fragments. BK=32,
// global_load_lds width-16 staging, 16 MFMA/wave/step, 16 KB LDS.
// EPI: 0 = +bias, 1 = +bias then gelu, 2 = +bias +res. OF32: f32 vs bf16 output.
template<int EPI, bool OF32>
__global__ __launch_bounds__(256) void gemm128(const unsigned short* __restrict__ A,
                                               const unsigned short* __restrict__ Bt,
                                               const float* __restrict__ bias,
                                               const float* __restrict__ res,
                                               void* __restrict__ Cout_,
                                               int M, int Nv, int K) {
    __shared__ unsigned short Als[128 * 32];
    __shared__ unsigned short Bls[128 * 32];
    int tid  = threadIdx.x;
    int lane = tid & 63;
    int wave = tid >> 6;
    int quad = lane >> 4;
    int l16  = lane & 15;
    int m0 = blockIdx.x * 128;
    int n0 = blockIdx.y * 128;
    int wr = (wave & 1) * 64;
    int wc = (wave >> 1) * 64;

    f32x4 acc[4][4];
    #pragma unroll
    for (int i = 0; i < 4; ++i)
        #pragma unroll
        for (int j = 0; j < 4; ++j)
            acc[i][j] = (f32x4){0.f, 0.f, 0.f, 0.f};

    const unsigned short* Ag[2];
    const unsigned short* Bg[2];
    unsigned short* Alp[2];
    unsigned short* Blp[2];
    #pragma unroll
    for (int u = 0; u < 2; ++u) {
        int chunk = u * 256 + wave * 64 + lane;
        int row = chunk >> 2, slot = (chunk & 3) * 8;
        Ag[u] = A  + (size_t)(m0 + row) * K + slot;
        Bg[u] = Bt + (size_t)(n0 + row) * K + slot;
        Alp[u] = &Als[(u * 256 + wave * 64) * 8];
        Blp[u] = &Bls[(u * 256 + wave * 64) * 8];
    }

    for (int k0 = 0; k0 < K; k0 += 32) {
        __syncthreads();
        #pragma unroll
        for (int u = 0; u < 2; ++u) {
            __builtin_amdgcn_global_load_lds(
                (const __attribute__((address_space(1))) void*)(Ag[u] + k0),
                (__attribute__((address_space(3))) void*)Alp[u], 16, 0, 0);
            __builtin_amdgcn_global_load_lds(
                (const __attribute__((address_space(1))) void*)(Bg[u] + k0),
                (__attribute__((address_space(3))) void*)Blp[u], 16, 0, 0);
        }
        __builtin_amdgcn_s_waitcnt(0);
        __syncthreads();

        bf16x8 af[4];
        bf16x8 bfr[4];
        #pragma unroll
        for (int i = 0; i < 4; ++i)
            af[i] = *(const bf16x8*)&Als[(wr + i * 16 + l16) * 32 + quad * 8];
        #pragma unroll
        for (int j = 0; j < 4; ++j)
            bfr[j] = *(const bf16x8*)&Bls[(wc + j * 16 + l16) * 32 + quad * 8];
        #pragma unroll
        for (int i = 0; i < 4; ++i)
            #pragma unroll
            for (int j = 0; j < 4; ++j)
                acc[i][j] = __builtin_amdgcn_mfma_f32_16x16x32_bf16(af[i], bfr[j], acc[i][j], 0, 0, 0);
    }

    #pragma unroll
    for (int j = 0; j < 4; ++j) {
        int col = n0 + wc + j * 16 + l16;
        float bv = bias[col];
        #pragma unroll
        for (int i = 0; i < 4; ++i) {
            #pragma unroll
            for (int r = 0; r < 4; ++r) {
                int row = m0 + wr + i * 16 + quad * 4 + r;
                float val = acc[i][j][r] + bv;
                if (EPI == 2) val += res[(size_t)row * Nv + col];
                if (EPI == 1) val = gelu_f(val);
                if (OF32) ((float*)Cout_)[(size_t)row * Nv + col] = val;
                else      ((unsigned short*)Cout_)[(size_t)row * Nv + col] = f2bf(val);
            }
        }
    }
}

// ---------------- fused LN1 + offsets/logits GEMM: oa = LN(x) @ [Woff|Wa] + b ---------
__global__ __launch_bounds__(512) void lnoa_k(
        const float* __restrict__ x, const float* __restrict__ lw, const float* __restrict__ lb,
        const unsigned short* __restrict__ woas, const float* __restrict__ b_oa,
        unsigned short* __restrict__ oa) {
    __shared__ char lds_raw[33280];
    unsigned short* hblob = (unsigned short*)lds_raw;
    int t = threadIdx.x;
    int lane = t & 63, wave = t >> 6;
    int quad = lane >> 4, l16 = lane & 15;
    int row0 = blockIdx.x * 64;

    ln_stage(x + (size_t)row0 * CC, lw, lb, hblob, t);
    __syncthreads();

    if (wave < 6) {
        f32x4 acc[4];
        #pragma unroll
        for (int qt = 0; qt < 4; ++qt) acc[qt] = (f32x4){0.f, 0.f, 0.f, 0.f};
        #pragma unroll
        for (int kb = 0; kb < 8; ++kb) {
            bf16x8 a1 = *(const bf16x8*)(woas + ((size_t)(kb * 4 + quad) * 128 + wave * 16 + l16) * 8);
            #pragma unroll
            for (int qt = 0; qt < 4; ++qt) {
                bf16x8 bf = *(const bf16x8*)((char*)hblob + (kb * 4 + quad) * 1040 + (qt * 16 + l16) * 16);
                acc[qt] = __builtin_amdgcn_mfma_f32_16x16x32_bf16(a1, bf, acc[qt], 0, 0, 0);
            }
        }
        int n0 = wave * 16 + quad * 4;
        float4 bb = *(const float4*)(b_oa + n0);
        const float* bp = (const float*)&bb;
        #pragma unroll
        for (int qt = 0; qt < 4; ++qt) {
            unsigned long long pk = 0;
            #pragma unroll
            for (int r = 0; r < 4; ++r)
                pk |= ((unsigned long long)f2bf(acc[qt][r] + bp[r])) << (16 * r);
            *(unsigned long long*)(oa + (size_t)(row0 + qt * 16 + l16) * 96 + n0) = pk;
        }
    }
}

// ---------------- fused sampling + Wout GEMM + residual: x2 = x + samp@Wout + bout -----
// Also computes LN2 row stats in the epilogue and writes xln = LN2(x2) bf16.
__global__ __launch_bounds__(512) void samwout_k(
        const unsigned short* __restrict__ v,    // (NB, HW, C) bf16
        const float* __restrict__ ref,           // (R, 2) fp32
        const unsigned short* __restrict__ oa,   // (R, 96) bf16
        const unsigned short* __restrict__ woutS,
        const float* __restrict__ bout,
        const float* __restrict__ x,             // residual fp32
        float* __restrict__ x2,
        unsigned short* __restrict__ xln,        // (R, C) bf16
        const float* __restrict__ ln2w,
        const float* __restrict__ ln2b) {
    __shared__ char lds_raw[57856];
    unsigned short* hblob = (unsigned short*)lds_raw;            // 32 kq x 1040 B
    short4* sidx = (short4*)(lds_raw + 33280);                   // 1024 x 8 B
    float4* sw   = (float4*)(lds_raw + 41472);                   // 1024 x 16 B
    float* trans = (float*)lds_raw;                              // alias (epilogue, 32x260)

    int t = threadIdx.x;
    int lane = t & 63, wave = t >> 6;
    int quad = lane >> 4, l16 = lane & 15;
    int row0 = blockIdx.x * 64;
    int nb = blockIdx.x / (LQ / 64);             // batch, block-uniform

    for (int half = 0; half < 2; ++half) {
        int rbase = half * 32;
        // ---- phase A: 1024 tuples (32q x 8h x 4p), 2 per thread ----
        #pragma unroll
        for (int s = 0; s < 2; ++s) {
            int e = t + s * 512;
            int q = e >> 5, sub = e & 31, h = sub >> 2, p = sub & 3;
            int row = row0 + rbase + q;
            float refx = ref[row * 2 + 0];
            float refy = ref[row * 2 + 1];
            const unsigned short* oar = oa + (size_t)row * 96;
            float ox = bf2f(oar[(h * 4 + p) * 2 + 0]);
            float oy = bf2f(oar[(h * 4 + p) * 2 + 1]);
            float l  = bf2f(oar[64 + h * 4 + p]);
            float m = fmaxf(l, __shfl_xor(l, 1));
            m = fmaxf(m, __shfl_xor(m, 2));
            float ee = __expf(l - m);
            float ss = ee + __shfl_xor(ee, 1);
            ss = ss + __shfl_xor(ss, 2);
            float wp = ee / ss;

            float gx = (refx + ox * (1.0f / WW)) * WW - 0.5f;
            float gy = (refy + oy * (1.0f / HH)) * HH - 0.5f;
            float fx = floorf(gx), fy = floorf(gy);
            float wx = gx - fx, wy = gy - fy;
            int x0 = (int)fx, y0 = (int)fy;
            int x1 = x0 + 1, y1 = y0 + 1;
            bool vx0 = (unsigned)x0 < WW, vx1 = (unsigned)x1 < WW;
            bool vy0 = (unsigned)y0 < HH, vy1 = (unsigned)y1 < HH;
            float w00 = (vx0 && vy0) ? wp * (1.f - wx) * (1.f - wy) : 0.f;
            float w10 = (vx1 && vy0) ? wp * wx * (1.f - wy)         : 0.f;
            float w01 = (vx0 && vy1) ? wp * (1.f - wx) * wy         : 0.f;
            float w11 = (vx1 && vy1) ? wp * wx * wy                 : 0.f;
            int cx0 = min(max(x0, 0), WW - 1), cx1 = min(max(x1, 0), WW - 1);
            int cy0 = min(max(y0, 0), HH - 1), cy1 = min(max(y1, 0), HH - 1);
            sidx[e] = (short4){(short)(cy0 * WW + cx0), (short)(cy0 * WW + cx1),
                               (short)(cy1 * WW + cx0), (short)(cy1 * WW + cx1)};
            sw[e]   = (float4){w00, w10, w01, w11};
        }
        __syncthreads();
        // ---- phase B: gather, 2 (q,h,cg) combos per thread ----
        #pragma unroll
        for (int s = 0; s < 2; ++s) {
            int c = t + s * 512;
            int q = c >> 5, sub = c & 31, h = sub >> 2, cg = sub & 3;
            const unsigned short* base = v + (size_t)nb * HWSZ * CC + h * 32 + cg * 8;
            float acc[8];
            #pragma unroll
            for (int j = 0; j < 8; ++j) acc[j] = 0.f;
            #pragma unroll
            for (int p = 0; p < 4; ++p) {
                int e = q * 32 + h * 4 + p;
                short4 I = sidx[e];
                float4 Wt = sw[e];
                const short* Ip = (const short*)&I;
                const float* Wp = (const float*)&Wt;
                #pragma unroll
                for (int cn = 0; cn < 4; ++cn) {
                    bf16x8 u = *(const bf16x8*)(base + (size_t)(unsigned short)Ip[cn] * CC);
                    float wgt = Wp[cn];
                    #pragma unroll
                    for (int j = 0; j < 8; ++j)
                        acc[j] += wgt * bf2f((unsigned short)u[j]);
                }
            }
            bf16x8 o;
            #pragma unroll
            for (int j = 0; j < 8; ++j) o[j] = (short)f2bf(acc[j]);
            *(bf16x8*)((char*)hblob + sub * 1040 + (rbase + q) * 16) = o;
        }
        __syncthreads();
    }

    // ---- Wout MFMA: K=256, 8 waves x 32 cols ----
    f32x4 acc2[2][4];
    #pragma unroll
    for (int a = 0; a < 2; ++a)
        #pragma unroll
        for (int b = 0; b < 4; ++b)
            acc2[a][b] = (f32x4){0.f, 0.f, 0.f, 0.f};
    #pragma unroll
    for (int kb = 0; kb < 8; ++kb) {
        bf16x8 a2[2];
        bf16x8 bf[4];
        #pragma unroll
        for (int ct = 0; ct < 2; ++ct)
            a2[ct] = *(const bf16x8*)(woutS + ((size_t)(kb * 4 + quad) * 256 + wave * 32 + ct * 16 + l16) * 8);
        #pragma unroll
        for (int qt = 0; qt < 4; ++qt)
            bf[qt] = *(const bf16x8*)((char*)hblob + (kb * 4 + quad) * 1040 + (qt * 16 + l16) * 16);
        #pragma unroll
        for (int ct = 0; ct < 2; ++ct)
            #pragma unroll
            for (int qt = 0; qt < 4; ++qt)
                acc2[ct][qt] = __builtin_amdgcn_mfma_f32_16x16x32_bf16(a2[ct], bf[qt], acc2[ct][qt], 0, 0, 0);
    }

    // ---- epilogue: transpose via LDS, + x + bout -> x2; LN2 stats -> xln bf16 ----
    for (int p = 0; p < 2; ++p) {
        __syncthreads();
        #pragma unroll
        for (int qi = 0; qi < 2; ++qi) {
            int qt = p * 2 + qi;
            int qlocal = qt * 16 + l16 - p * 32;
            #pragma unroll
            for (int ct = 0; ct < 2; ++ct) {
                int c4 = wave * 8 + ct * 4 + quad;
                *(f32x4*)(trans + qlocal * 260 + c4 * 4) = acc2[ct][qt];
            }
        }
        __syncthreads();
        int rr = t >> 4;                          // 0..31
        int c4b = t & 15;
        int row = row0 + p * 32 + rr;
        float4 ov[4];
        float s = 0.f, s2 = 0.f;
        #pragma unroll
        for (int i = 0; i < 4; ++i) {
            int c4 = i * 16 + c4b;
            f32x4 vv = *(const f32x4*)(trans + rr * 260 + c4 * 4);
            int c = c4 * 4;
            float4 xv = *(const float4*)(x + (size_t)row * CC + c);
            float4 bb = *(const float4*)(bout + c);
            float4 o;
            o.x = vv[0] + xv.x + bb.x;
            o.y = vv[1] + xv.y + bb.y;
            o.z = vv[2] + xv.z + bb.z;
            o.w = vv[3] + xv.w + bb.w;
            *(float4*)(x2 + (size_t)row * CC + c) = o;
            ov[i] = o;
            s  += o.x + o.y + o.z + o.w;
            s2 += o.x*o.x + o.y*o.y + o.z*o.z + o.w*o.w;
        }
        #pragma unroll
        for (int m = 1; m < 16; m <<= 1) {
            s  += __shfl_xor(s,  m);
            s2 += __shfl_xor(s2, m);
        }
        float mean = s * (1.0f / CC);
        float var  = s2 * (1.0f / CC) - mean * mean;
        float rstd = rsqrtf(fmaxf(var, 0.0f) + 1e-5f);
        #pragma unroll
        for (int i = 0; i < 4; ++i) {
            int c = (i * 16 + c4b) * 4;
            float4 wv = *(const float4*)(ln2w + c);
            float4 bv = *(const float4*)(ln2b + c);
            ushort4 u;
            u.x = f2bf((ov[i].x - mean) * rstd * wv.x + bv.x);
            u.y = f2bf((ov[i].y - mean) * rstd * wv.y + bv.y);
            u.z = f2bf((ov[i].z - mean) * rstd * wv.z + bv.z);
            u.w = f2bf((ov[i].w - mean) * rstd * wv.w + bv.w);
            *(ushort4*)(xln + (size_t)row * CC + c) = u;
        }
    }
}

// ---------------- fused MLP: out = x2 + gelu(xln@W1+b1)@W2 + b2, h kept in LDS --------
// 128-row blocks, grid 200 (< 256 CUs, all co-resident), weight L2 stream 200 MB total
// (~6 µs floor), h never leaves LDS. Per hc (8 chunks of 128 hid): s1 = 64 MFMA/wave +
// w1s frag loads + gelu -> h LDS; barrier; s2 = 64 MFMA/wave + w2s loads -> acc; barrier.
// LDS 99 KB (xblob 32kq x 2064B, hbuf 16kq x 2064B; 2064 = 129 granules, bank-clean).
__global__ __launch_bounds__(512, 2) void mlpf_k(
        const unsigned short* __restrict__ xln,  // (R, C) bf16 = LN2(x2)
        const float* __restrict__ x2,            // residual fp32
        const unsigned short* __restrict__ w1s,  // frag-swizzled (256 x 1024)
        const float* __restrict__ b1,
        const unsigned short* __restrict__ w2s,  // frag-swizzled (1024 x 256)
        const float* __restrict__ b2,
        float* __restrict__ out) {
    __shared__ char lds_raw[99072];
    char* xblob = lds_raw;                       // 32 kq x 2064 B (128 rows x 16 B + pad)
    char* hbuf  = lds_raw + 66048;               // 16 kq x 2064 B
    float* trans = (float*)lds_raw;              // epilogue alias: 64 x 260 f32 (66560 B)

    int t = threadIdx.x;
    int lane = t & 63, wave = t >> 6;
    int quad = lane >> 4, l16 = lane & 15;
    int row0 = blockIdx.x * 128;

    // ---- stage xln tile (128 x 256 bf16) fragment-major via global_load_lds ----
    // chunk c (0..4095): kq = c>>7, row = c&127; fragment k-base = kq*8 (== prep swizzle).
    // LDS dest is wave-uniform (lane bits masked); global src is per-lane.
    #pragma unroll
    for (int s = 0; s < 8; ++s) {
        int c  = s * 512 + t;
        int cb = c & ~63;                        // wave-uniform
        const unsigned short* src = xln + (size_t)(row0 + (c & 127)) * CC + (c >> 7) * 8;
        char* dst = xblob + (cb >> 7) * 2064 + (cb & 127) * 16;
        __builtin_amdgcn_global_load_lds(
            (const __attribute__((address_space(1))) void*)src,
            (__attribute__((address_space(3))) void*)dst, 16, 0, 0);
    }
    __builtin_amdgcn_s_waitcnt(0);
    __syncthreads();

    f32x4 acc2[2][8];
    #pragma unroll
    for (int a = 0; a < 2; ++a)
        #pragma unroll
        for (int b = 0; b < 8; ++b)
            acc2[a][b] = (f32x4){0.f, 0.f, 0.f, 0.f};

    for (int hc = 0; hc < 8; ++hc) {
        // ---- s1: h[hc] = gelu(xln @ W1[:, hc*128..+128) + b1), fragment-major in hbuf --
        {
            f32x4 a[8];
            #pragma unroll
            for (int qt = 0; qt < 8; ++qt) a[qt] = (f32x4){0.f, 0.f, 0.f, 0.f};
            #pragma unroll
            for (int kb = 0; kb < 8; ++kb) {
                bf16x8 w = *(const bf16x8*)(w1s + ((size_t)(kb * 4 + quad) * 1024 + hc * 128 + wave * 16 + l16) * 8);
                #pragma unroll
                for (int qt = 0; qt < 8; ++qt) {
                    bf16x8 bf = *(const bf16x8*)(xblob + (kb * 4 + quad) * 2064 + (qt * 16 + l16) * 16);
                    a[qt] = __builtin_amdgcn_mfma_f32_16x16x32_bf16(w, bf, a[qt], 0, 0, 0);
                }
            }
            int hl = wave * 16 + quad * 4;
            float4 bb = *(const float4*)(b1 + hc * 128 + hl);
            const float* bp = (const float*)&bb;
            #pragma unroll
            for (int qt = 0; qt < 8; ++qt) {
                unsigned long long pk = 0;
                #pragma unroll
                for (int r = 0; r < 4; ++r) {
                    float val = gelu_f(a[qt][r] + bp[r]);
                    pk |= ((unsigned long long)f2bf(val)) << (16 * r);
                }
                *(unsigned long long*)(hbuf + (hl >> 3) * 2064 + (qt * 16 + l16) * 16 + (hl & 7) * 2) = pk;
            }
        }
        __syncthreads();
        // ---- s2: acc2 += h[hc] @ W2[hc*128 rows] ----
        #pragma unroll
        for (int k2 = 0; k2 < 4; ++k2) {
            bf16x8 w[2];
            #pragma unroll
            for (int ct = 0; ct < 2; ++ct)
                w[ct] = *(const bf16x8*)(w2s + ((size_t)((hc * 4 + k2) * 4 + quad) * 256 + wave * 32 + ct * 16 + l16) * 8);
            #pragma unroll
            for (int qt = 0; qt < 8; ++qt) {
                bf16x8 bf = *(const bf16x8*)(hbuf + (k2 * 4 + quad) * 2064 + (qt * 16 + l16) * 16);
                #pragma unroll
                for (int ct = 0; ct < 2; ++ct)
                    acc2[ct][qt] = __builtin_amdgcn_mfma_f32_16x16x32_bf16(w[ct], bf, acc2[ct][qt], 0, 0, 0);
            }
        }
        __syncthreads();
    }

    // ---- epilogue: 2 passes of 64 rows; transpose via LDS, + x2 + b2, coalesced f32 ----
    #pragma unroll
    for (int p = 0; p < 2; ++p) {
        __syncthreads();
        #pragma unroll
        for (int qi = 0; qi < 4; ++qi) {
            int qt = p * 4 + qi;
            int qlocal = qt * 16 + l16 - p * 64;
            #pragma unroll
            for (int ct = 0; ct < 2; ++ct) {
                int c4 = wave * 8 + ct * 4 + quad;
                *(f32x4*)(trans + qlocal * 260 + c4 * 4) = acc2[ct][qt];
            }
        }
        __syncthreads();
        int rr = t >> 3, c8 = t & 7;             // 64 rows x 8 col-groups
        int row = row0 + p * 64 + rr;
        #pragma unroll
        for (int i = 0; i < 8; ++i) {
            int c = (c8 + i * 8) * 4;
            f32x4 vv = *(const f32x4*)(trans + rr * 260 + c);
            float4 xv = *(const float4*)(x2 + (size_t)row * CC + c);
            float4 bb = *(const float4*)(b2 + c);
            float4 o;
            o.x = vv[0] + xv.x + bb.x;
            o.y = vv[1] + xv.y + bb.y;
            o.z = vv[2] + xv.z + bb.z;
            o.w = vv[3] + xv.w + bb.w;
            *(float4*)(out + (size_t)row * CC + c) = o;
        }
    }
}

extern "C" void kernel_launch(void* const* d_in, const int* in_sizes, int n_in,
                              void* d_out, int out_size, void* d_ws, size_t ws_size,
                              hipStream_t stream) {
    const float* x     = (const float*)d_in[0];
    const float* ref   = (const float*)d_in[1];
    const float* value = (const float*)d_in[2];
    const float* ln1w  = (const float*)d_in[5];
    const float* ln1b  = (const float*)d_in[6];
    const float* ln2w  = (const float*)d_in[7];
    const float* ln2b  = (const float*)d_in[8];
    const float* Wv    = (const float*)d_in[9];
    const float* bv    = (const float*)d_in[10];
    const float* Woff  = (const float*)d_in[11];
    const float* boff  = (const float*)d_in[12];
    const float* Wa    = (const float*)d_in[13];
    const float* ba    = (const float*)d_in[14];
    const float* Wout  = (const float*)d_in[15];
    const float* bout  = (const float*)d_in[16];
    const float* W1    = (const float*)d_in[17];
    const float* b1    = (const float*)d_in[18];
    const float* W2    = (const float*)d_in[19];
    const float* b2    = (const float*)d_in[20];

    // ---- workspace layout (bytes), total 58,720,768 ----
    // xln reuses the val_b slot (dead after the value-projection GEMM).
    char* ws = (char*)d_ws;
    unsigned short* wtv_b  = (unsigned short*)(ws + 0);          // 131072
    unsigned short* wouts_b= (unsigned short*)(ws + 131072);     // 131072
    unsigned short* w1s_b  = (unsigned short*)(ws + 262144);     // 524288
    unsigned short* w2s_b  = (unsigned short*)(ws + 786432);     // 524288
    unsigned short* woas_b = (unsigned short*)(ws + 1310720);    // 65536
    float*          b_oa   = (float*)         (ws + 1376256);    // 512
    float*          x2_f   = (float*)         (ws + 1376768);    // 26,214,400
    unsigned short* val_b  = (unsigned short*)(ws + 27591168);   // 13,107,200 (val | xln)
    unsigned short* v_b    = (unsigned short*)(ws + 40698368);   // 13,107,200
    unsigned short* oa_b   = (unsigned short*)(ws + 53805568);   // 4,915,200 -> 58,720,768

    // one-shot weight prep (transpose + fragment swizzles + bias concat)
    prep_k<<<561, 256, 0, stream>>>(Wv, Wout, W1, W2, Woff, Wa, boff, ba,
                                    wtv_b, wouts_b, w1s_b, w2s_b, woas_b, b_oa);
    // value fp32 -> bf16
    cvt_k<<<(RTOT*CC/4 + 255) / 256, 256, 0, stream>>>(value, val_b, RTOT*CC/4);
    // value projection -> v_b  (128x128-tile GEMM)
    gemm128<0, false><<<dim3(RTOT/128, 2), 256, 0, stream>>>(val_b, wtv_b, bv, nullptr, v_b, RTOT, 256, 256);
    // fused LN1 + offsets/logits -> oa_b
    lnoa_k<<<RTOT/64, 512, 0, stream>>>(x, ln1w, ln1b, woas_b, b_oa, oa_b);

    unsigned short* xln_b = val_b;   // val_b dead after value projection
    // fused sampling + Wout + residual -> x2, + LN2 -> xln
    samwout_k<<<RTOT/64, 512, 0, stream>>>(v_b, ref, oa_b, wouts_b, bout, x, x2_f,
                                           xln_b, ln2w, ln2b);
    // fused MLP (h stays in LDS) -> out
    mlpf_k<<<RTOT/128, 512, 0, stream>>>(xln_b, x2_f, w1s_b, b1, w2s_b, b2, (float*)d_out);
}

// Round 8
// 238.082 us; speedup vs baseline: 1.1268x; 1.1268x over previous
//
#include <hip/hip_runtime.h>

// Problem constants (setup_inputs fixed: N=4, Lq=6400, C=256, H=W=80)
#define NB    4
#define LQ    6400
#define CC    256
#define HH    80
#define WW    80
#define HWSZ  (HH*WW)
#define RTOT  (NB*LQ)        // 25600 rows
#define HID   1024

typedef __attribute__((ext_vector_type(8))) short bf16x8;   // 8 bf16 = 4 VGPRs
typedef __attribute__((ext_vector_type(4))) float f32x4;

__device__ __forceinline__ float bf2f(unsigned short u) {
    unsigned int i = ((unsigned int)u) << 16;
    float f; __builtin_memcpy(&f, &i, 4); return f;
}
__device__ __forceinline__ unsigned short f2bf(float f) {
    unsigned int i; __builtin_memcpy(&i, &f, 4);
    unsigned int r = i + 0x7fffu + ((i >> 16) & 1u);   // RNE
    return (unsigned short)(r >> 16);
}

// tanh-form GELU: |err| vs exact-erf gelu ~3e-4 << bf16 quantization of h.
__device__ __forceinline__ float gelu_f(float v) {
    float u = v * (0.7978845608f + 0.0356774081f * (v * v));
    return v / (1.0f + __expf(-2.0f * u));
}

// ---------------- fp32 -> bf16 convert (4 elems/thread) ----------------
__global__ void cvt_k(const float* __restrict__ in, unsigned short* __restrict__ out, int n4) {
    int i = blockIdx.x * 256 + threadIdx.x;
    if (i < n4) {
        float4 u = ((const float4*)in)[i];
        ushort4 o;
        o.x = f2bf(u.x); o.y = f2bf(u.y); o.z = f2bf(u.z); o.w = f2bf(u.w);
        ((ushort4*)out)[i] = o;
    }
}

// ---------------- one-shot weight prep (transpose + fragment swizzles + bias cat) ------
// swizzle layout: group g -> n = g%N, kq = g/N; dst[g*8+j] = bf16(src[(kq*8+j)*N + n])
// — the exact VGPR image an A-fragment wants.
__global__ void prep_k(const float* __restrict__ Wv,   const float* __restrict__ Wout,
                       const float* __restrict__ W1,   const float* __restrict__ W2,
                       const float* __restrict__ Woff, const float* __restrict__ Wa,
                       const float* __restrict__ boff, const float* __restrict__ ba,
                       unsigned short* __restrict__ wtv,  unsigned short* __restrict__ woutS,
                       unsigned short* __restrict__ w1s,  unsigned short* __restrict__ w2s,
                       unsigned short* __restrict__ woas, float* __restrict__ b_oa) {
    int idx = blockIdx.x * 256 + threadIdx.x;
    if (idx < 65536) {                          // wtv transpose: wtv[n*256+k] = Wv[k*256+n]
        int n = idx >> 8, k = idx & 255;
        wtv[idx] = f2bf(Wv[(size_t)k * 256 + n]);
        return;
    }
    idx -= 65536;
    if (idx < 32768) {                          // w1s swizzle (K=256, N=1024)
        int n = idx & 1023, kq = idx >> 10;
        int kb = kq * 8;
        unsigned short* d = w1s + (size_t)idx * 8;
        #pragma unroll
        for (int j = 0; j < 8; ++j) d[j] = f2bf(W1[(size_t)(kb + j) * 1024 + n]);
        return;
    }
    idx -= 32768;
    if (idx < 32768) {                          // w2s swizzle (K=1024, N=256)
        int n = idx & 255, kq = idx >> 8;
        int kb = kq * 8;
        unsigned short* d = w2s + (size_t)idx * 8;
        #pragma unroll
        for (int j = 0; j < 8; ++j) d[j] = f2bf(W2[(size_t)(kb + j) * 256 + n]);
        return;
    }
    idx -= 32768;
    if (idx < 8192) {                           // woutS swizzle (K=256, N=256)
        int n = idx & 255, kq = idx >> 8;
        int kb = kq * 8;
        unsigned short* d = woutS + (size_t)idx * 8;
        #pragma unroll
        for (int j = 0; j < 8; ++j) d[j] = f2bf(Wout[(size_t)(kb + j) * 256 + n]);
        return;
    }
    idx -= 8192;
    if (idx < 4096) {                           // woas swizzle (K=256, Npad=128: Woff|Wa|0)
        int n = idx & 127, kq = idx >> 7;
        int kb = kq * 8;
        unsigned short* d = woas + (size_t)idx * 8;
        #pragma unroll
        for (int j = 0; j < 8; ++j) {
            float v = 0.f;
            if (n < 64)      v = Woff[(size_t)(kb + j) * 64 + n];
            else if (n < 96) v = Wa[(size_t)(kb + j) * 32 + (n - 64)];
            d[j] = f2bf(v);
        }
        return;
    }
    idx -= 4096;
    if (idx < 96) b_oa[idx] = idx < 64 ? boff[idx] : ba[idx - 64];
}

// ---------------- shared LN stage: 64 rows fp32 -> fragment-major bf16 hblob ----------
// 512 threads: 8 threads/row; hblob 32 kq x 1040 B stride (odd 16B-granule -> bank-clean).
__device__ __forceinline__ void ln_stage(const float* __restrict__ xbase,  // + row0*CC
                                         const float* __restrict__ lw,
                                         const float* __restrict__ lb,
                                         unsigned short* hblob, int t) {
    int r = t >> 3, sub = t & 7;
    const float* xr = xbase + (size_t)r * CC;
    float4 xv[4][2];
    float s = 0.f, s2 = 0.f;
    #pragma unroll
    for (int jj = 0; jj < 4; ++jj) {
        #pragma unroll
        for (int u = 0; u < 2; ++u) {
            float4 v = *(const float4*)(xr + sub * 8 + jj * 64 + u * 4);
            xv[jj][u] = v;
            s  += v.x + v.y + v.z + v.w;
            s2 += v.x*v.x + v.y*v.y + v.z*v.z + v.w*v.w;
        }
    }
    #pragma unroll
    for (int m = 1; m < 8; m <<= 1) {
        s  += __shfl_xor(s,  m);
        s2 += __shfl_xor(s2, m);
    }
    float mean = s * (1.0f / CC);
    float var  = s2 * (1.0f / CC) - mean * mean;
    float rstd = rsqrtf(fmaxf(var, 0.0f) + 1e-5f);
    #pragma unroll
    for (int jj = 0; jj < 4; ++jj) {
        int c0 = sub * 8 + jj * 64;
        float4 w0 = *(const float4*)(lw + c0);
        float4 w1 = *(const float4*)(lw + c0 + 4);
        float4 bb0 = *(const float4*)(lb + c0);
        float4 bb1 = *(const float4*)(lb + c0 + 4);
        bf16x8 o;
        o[0] = (short)f2bf((xv[jj][0].x - mean) * rstd * w0.x + bb0.x);
        o[1] = (short)f2bf((xv[jj][0].y - mean) * rstd * w0.y + bb0.y);
        o[2] = (short)f2bf((xv[jj][0].z - mean) * rstd * w0.z + bb0.z);
        o[3] = (short)f2bf((xv[jj][0].w - mean) * rstd * w0.w + bb0.w);
        o[4] = (short)f2bf((xv[jj][1].x - mean) * rstd * w1.x + bb1.x);
        o[5] = (short)f2bf((xv[jj][1].y - mean) * rstd * w1.y + bb1.y);
        o[6] = (short)f2bf((xv[jj][1].z - mean) * rstd * w1.z + bb1.z);
        o[7] = (short)f2bf((xv[jj][1].w - mean) * rstd * w1.w + bb1.w);
        int kq = sub + jj * 8;
        *(bf16x8*)((char*)hblob + kq * 1040 + r * 16) = o;
    }
}

// ---------------- 128x128-tile GEMM (value projection) ----------------
template<int EPI, bool OF32>
__global__ __launch_bounds__(256) void gemm128(const unsigned short* __restrict__ A,
                                               const unsigned short* __restrict__ Bt,
                                               const float* __restrict__ bias,
                                               const float* __restrict__ res,
                                               void* __restrict__ Cout_,
                                               int M, int Nv, int K) {
    __shared__ unsigned short Als[128 * 32];
    __shared__ unsigned short Bls[128 * 32];
    int tid  = threadIdx.x;
    int lane = tid & 63;
    int wave = tid >> 6;
    int quad = lane >> 4;
    int l16  = lane & 15;
    int m0 = blockIdx.x * 128;
    int n0 = blockIdx.y * 128;
    int wr = (wave & 1) * 64;
    int wc = (wave >> 1) * 64;

    f32x4 acc[4][4];
    #pragma unroll
    for (int i = 0; i < 4; ++i)
        #pragma unroll
        for (int j = 0; j < 4; ++j)
            acc[i][j] = (f32x4){0.f, 0.f, 0.f, 0.f};

    const unsigned short* Ag[2];
    const unsigned short* Bg[2];
    unsigned short* Alp[2];
    unsigned short* Blp[2];
    #pragma unroll
    for (int u = 0; u < 2; ++u) {
        int chunk = u * 256 + wave * 64 + lane;
        int row = chunk >> 2, slot = (chunk & 3) * 8;
        Ag[u] = A  + (size_t)(m0 + row) * K + slot;
        Bg[u] = Bt + (size_t)(n0 + row) * K + slot;
        Alp[u] = &Als[(u * 256 + wave * 64) * 8];
        Blp[u] = &Bls[(u * 256 + wave * 64) * 8];
    }

    for (int k0 = 0; k0 < K; k0 += 32) {
        __syncthreads();
        #pragma unroll
        for (int u = 0; u < 2; ++u) {
            __builtin_amdgcn_global_load_lds(
                (const __attribute__((address_space(1))) void*)(Ag[u] + k0),
                (__attribute__((address_space(3))) void*)Alp[u], 16, 0, 0);
            __builtin_amdgcn_global_load_lds(
                (const __attribute__((address_space(1))) void*)(Bg[u] + k0),
                (__attribute__((address_space(3))) void*)Blp[u], 16, 0, 0);
        }
        __builtin_amdgcn_s_waitcnt(0);
        __syncthreads();

        bf16x8 af[4];
        bf16x8 bfr[4];
        #pragma unroll
        for (int i = 0; i < 4; ++i)
            af[i] = *(const bf16x8*)&Als[(wr + i * 16 + l16) * 32 + quad * 8];
        #pragma unroll
        for (int j = 0; j < 4; ++j)
            bfr[j] = *(const bf16x8*)&Bls[(wc + j * 16 + l16) * 32 + quad * 8];
        #pragma unroll
        for (int i = 0; i < 4; ++i)
            #pragma unroll
            for (int j = 0; j < 4; ++j)
                acc[i][j] = __builtin_amdgcn_mfma_f32_16x16x32_bf16(af[i], bfr[j], acc[i][j], 0, 0, 0);
    }

    #pragma unroll
    for (int j = 0; j < 4; ++j) {
        int col = n0 + wc + j * 16 + l16;
        float bv = bias[col];
        #pragma unroll
        for (int i = 0; i < 4; ++i) {
            #pragma unroll
            for (int r = 0; r < 4; ++r) {
                int row = m0 + wr + i * 16 + quad * 4 + r;
                float val = acc[i][j][r] + bv;
                if (EPI == 2) val += res[(size_t)row * Nv + col];
                if (EPI == 1) val = gelu_f(val);
                if (OF32) ((float*)Cout_)[(size_t)row * Nv + col] = val;
                else      ((unsigned short*)Cout_)[(size_t)row * Nv + col] = f2bf(val);
            }
        }
    }
}

// ---------------- fused LN1 + offsets/logits GEMM: oa = LN(x) @ [Woff|Wa] + b ---------
__global__ __launch_bounds__(512) void lnoa_k(
        const float* __restrict__ x, const float* __restrict__ lw, const float* __restrict__ lb,
        const unsigned short* __restrict__ woas, const float* __restrict__ b_oa,
        unsigned short* __restrict__ oa) {
    __shared__ char lds_raw[33280];
    unsigned short* hblob = (unsigned short*)lds_raw;
    int t = threadIdx.x;
    int lane = t & 63, wave = t >> 6;
    int quad = lane >> 4, l16 = lane & 15;
    int row0 = blockIdx.x * 64;

    ln_stage(x + (size_t)row0 * CC, lw, lb, hblob, t);
    __syncthreads();

    if (wave < 6) {
        f32x4 acc[4];
        #pragma unroll
        for (int qt = 0; qt < 4; ++qt) acc[qt] = (f32x4){0.f, 0.f, 0.f, 0.f};
        #pragma unroll
        for (int kb = 0; kb < 8; ++kb) {
            bf16x8 a1 = *(const bf16x8*)(woas + ((size_t)(kb * 4 + quad) * 128 + wave * 16 + l16) * 8);
            #pragma unroll
            for (int qt = 0; qt < 4; ++qt) {
                bf16x8 bf = *(const bf16x8*)((char*)hblob + (kb * 4 + quad) * 1040 + (qt * 16 + l16) * 16);
                acc[qt] = __builtin_amdgcn_mfma_f32_16x16x32_bf16(a1, bf, acc[qt], 0, 0, 0);
            }
        }
        int n0 = wave * 16 + quad * 4;
        float4 bb = *(const float4*)(b_oa + n0);
        const float* bp = (const float*)&bb;
        #pragma unroll
        for (int qt = 0; qt < 4; ++qt) {
            unsigned long long pk = 0;
            #pragma unroll
            for (int r = 0; r < 4; ++r)
                pk |= ((unsigned long long)f2bf(acc[qt][r] + bp[r])) << (16 * r);
            *(unsigned long long*)(oa + (size_t)(row0 + qt * 16 + l16) * 96 + n0) = pk;
        }
    }
}

// ---------------- fused sampling + Wout GEMM + residual: x2 = x + samp@Wout + bout -----
// Also computes LN2 row stats in the epilogue and writes xln = LN2(x2) bf16.
__global__ __launch_bounds__(512) void samwout_k(
        const unsigned short* __restrict__ v,    // (NB, HW, C) bf16
        const float* __restrict__ ref,           // (R, 2) fp32
        const unsigned short* __restrict__ oa,   // (R, 96) bf16
        const unsigned short* __restrict__ woutS,
        const float* __restrict__ bout,
        const float* __restrict__ x,             // residual fp32
        float* __restrict__ x2,
        unsigned short* __restrict__ xln,        // (R, C) bf16
        const float* __restrict__ ln2w,
        const float* __restrict__ ln2b) {
    __shared__ char lds_raw[57856];
    unsigned short* hblob = (unsigned short*)lds_raw;            // 32 kq x 1040 B
    short4* sidx = (short4*)(lds_raw + 33280);                   // 1024 x 8 B
    float4* sw   = (float4*)(lds_raw + 41472);                   // 1024 x 16 B
    float* trans = (float*)lds_raw;                              // alias (epilogue, 32x260)

    int t = threadIdx.x;
    int lane = t & 63, wave = t >> 6;
    int quad = lane >> 4, l16 = lane & 15;
    int row0 = blockIdx.x * 64;
    int nb = blockIdx.x / (LQ / 64);             // batch, block-uniform

    for (int half = 0; half < 2; ++half) {
        int rbase = half * 32;
        // ---- phase A: 1024 tuples (32q x 8h x 4p), 2 per thread ----
        #pragma unroll
        for (int s = 0; s < 2; ++s) {
            int e = t + s * 512;
            int q = e >> 5, sub = e & 31, h = sub >> 2, p = sub & 3;
            int row = row0 + rbase + q;
            float refx = ref[row * 2 + 0];
            float refy = ref[row * 2 + 1];
            const unsigned short* oar = oa + (size_t)row * 96;
            float ox = bf2f(oar[(h * 4 + p) * 2 + 0]);
            float oy = bf2f(oar[(h * 4 + p) * 2 + 1]);
            float l  = bf2f(oar[64 + h * 4 + p]);
            float m = fmaxf(l, __shfl_xor(l, 1));
            m = fmaxf(m, __shfl_xor(m, 2));
            float ee = __expf(l - m);
            float ss = ee + __shfl_xor(ee, 1);
            ss = ss + __shfl_xor(ss, 2);
            float wp = ee / ss;

            float gx = (refx + ox * (1.0f / WW)) * WW - 0.5f;
            float gy = (refy + oy * (1.0f / HH)) * HH - 0.5f;
            float fx = floorf(gx), fy = floorf(gy);
            float wx = gx - fx, wy = gy - fy;
            int x0 = (int)fx, y0 = (int)fy;
            int x1 = x0 + 1, y1 = y0 + 1;
            bool vx0 = (unsigned)x0 < WW, vx1 = (unsigned)x1 < WW;
            bool vy0 = (unsigned)y0 < HH, vy1 = (unsigned)y1 < HH;
            float w00 = (vx0 && vy0) ? wp * (1.f - wx) * (1.f - wy) : 0.f;
            float w10 = (vx1 && vy0) ? wp * wx * (1.f - wy)         : 0.f;
            float w01 = (vx0 && vy1) ? wp * (1.f - wx) * wy         : 0.f;
            float w11 = (vx1 && vy1) ? wp * wx * wy                 : 0.f;
            int cx0 = min(max(x0, 0), WW - 1), cx1 = min(max(x1, 0), WW - 1);
            int cy0 = min(max(y0, 0), HH - 1), cy1 = min(max(y1, 0), HH - 1);
            sidx[e] = (short4){(short)(cy0 * WW + cx0), (short)(cy0 * WW + cx1),
                               (short)(cy1 * WW + cx0), (short)(cy1 * WW + cx1)};
            sw[e]   = (float4){w00, w10, w01, w11};
        }
        __syncthreads();
        // ---- phase B: gather, 2 (q,h,cg) combos per thread ----
        #pragma unroll
        for (int s = 0; s < 2; ++s) {
            int c = t + s * 512;
            int q = c >> 5, sub = c & 31, h = sub >> 2, cg = sub & 3;
            const unsigned short* base = v + (size_t)nb * HWSZ * CC + h * 32 + cg * 8;
            float acc[8];
            #pragma unroll
            for (int j = 0; j < 8; ++j) acc[j] = 0.f;
            #pragma unroll
            for (int p = 0; p < 4; ++p) {
                int e = q * 32 + h * 4 + p;
                short4 I = sidx[e];
                float4 Wt = sw[e];
                const short* Ip = (const short*)&I;
                const float* Wp = (const float*)&Wt;
                #pragma unroll
                for (int cn = 0; cn < 4; ++cn) {
                    bf16x8 u = *(const bf16x8*)(base + (size_t)(unsigned short)Ip[cn] * CC);
                    float wgt = Wp[cn];
                    #pragma unroll
                    for (int j = 0; j < 8; ++j)
                        acc[j] += wgt * bf2f((unsigned short)u[j]);
                }
            }
            bf16x8 o;
            #pragma unroll
            for (int j = 0; j < 8; ++j) o[j] = (short)f2bf(acc[j]);
            *(bf16x8*)((char*)hblob + sub * 1040 + (rbase + q) * 16) = o;
        }
        __syncthreads();
    }

    // ---- Wout MFMA: K=256, 8 waves x 32 cols ----
    f32x4 acc2[2][4];
    #pragma unroll
    for (int a = 0; a < 2; ++a)
        #pragma unroll
        for (int b = 0; b < 4; ++b)
            acc2[a][b] = (f32x4){0.f, 0.f, 0.f, 0.f};
    #pragma unroll
    for (int kb = 0; kb < 8; ++kb) {
        bf16x8 a2[2];
        bf16x8 bf[4];
        #pragma unroll
        for (int ct = 0; ct < 2; ++ct)
            a2[ct] = *(const bf16x8*)(woutS + ((size_t)(kb * 4 + quad) * 256 + wave * 32 + ct * 16 + l16) * 8);
        #pragma unroll
        for (int qt = 0; qt < 4; ++qt)
            bf[qt] = *(const bf16x8*)((char*)hblob + (kb * 4 + quad) * 1040 + (qt * 16 + l16) * 16);
        #pragma unroll
        for (int ct = 0; ct < 2; ++ct)
            #pragma unroll
            for (int qt = 0; qt < 4; ++qt)
                acc2[ct][qt] = __builtin_amdgcn_mfma_f32_16x16x32_bf16(a2[ct], bf[qt], acc2[ct][qt], 0, 0, 0);
    }

    // ---- epilogue: transpose via LDS, + x + bout -> x2; LN2 stats -> xln bf16 ----
    for (int p = 0; p < 2; ++p) {
        __syncthreads();
        #pragma unroll
        for (int qi = 0; qi < 2; ++qi) {
            int qt = p * 2 + qi;
            int qlocal = qt * 16 + l16 - p * 32;
            #pragma unroll
            for (int ct = 0; ct < 2; ++ct) {
                int c4 = wave * 8 + ct * 4 + quad;
                *(f32x4*)(trans + qlocal * 260 + c4 * 4) = acc2[ct][qt];
            }
        }
        __syncthreads();
        int rr = t >> 4;                          // 0..31
        int c4b = t & 15;
        int row = row0 + p * 32 + rr;
        float4 ov[4];
        float s = 0.f, s2 = 0.f;
        #pragma unroll
        for (int i = 0; i < 4; ++i) {
            int c4 = i * 16 + c4b;
            f32x4 vv = *(const f32x4*)(trans + rr * 260 + c4 * 4);
            int c = c4 * 4;
            float4 xv = *(const float4*)(x + (size_t)row * CC + c);
            float4 bb = *(const float4*)(bout + c);
            float4 o;
            o.x = vv[0] + xv.x + bb.x;
            o.y = vv[1] + xv.y + bb.y;
            o.z = vv[2] + xv.z + bb.z;
            o.w = vv[3] + xv.w + bb.w;
            *(float4*)(x2 + (size_t)row * CC + c) = o;
            ov[i] = o;
            s  += o.x + o.y + o.z + o.w;
            s2 += o.x*o.x + o.y*o.y + o.z*o.z + o.w*o.w;
        }
        #pragma unroll
        for (int m = 1; m < 16; m <<= 1) {
            s  += __shfl_xor(s,  m);
            s2 += __shfl_xor(s2, m);
        }
        float mean = s * (1.0f / CC);
        float var  = s2 * (1.0f / CC) - mean * mean;
        float rstd = rsqrtf(fmaxf(var, 0.0f) + 1e-5f);
        #pragma unroll
        for (int i = 0; i < 4; ++i) {
            int c = (i * 16 + c4b) * 4;
            float4 wv = *(const float4*)(ln2w + c);
            float4 bv = *(const float4*)(ln2b + c);
            ushort4 u;
            u.x = f2bf((ov[i].x - mean) * rstd * wv.x + bv.x);
            u.y = f2bf((ov[i].y - mean) * rstd * wv.y + bv.y);
            u.z = f2bf((ov[i].z - mean) * rstd * wv.z + bv.z);
            u.w = f2bf((ov[i].w - mean) * rstd * wv.w + bv.w);
            *(ushort4*)(xln + (size_t)row * CC + c) = u;
        }
    }
}

// ---------------- fused MLP, 64-row blocks: out = x2 + gelu(xln@W1+b1)@W2 + b2 --------
// Round-7 post-mortem: 128-row mlpf (grid 200 < 256 CUs, 99KB LDS -> 1 block/CU) was
// latency-dead at 85 µs / Occ 16%. This version: 64-row blocks, grid 400, LDS 66,560 B
// -> 2 blocks/CU, all 400 co-resident (16 waves/CU); weight L2 stream 400 MB (~12 µs
// floor). xln staged fragment-major via global_load_lds (64 rows x 16 B = exactly one
// wave-linear 1024 B per kq row -> the bank-clean 1040-stride layout works with async
// staging). s1/s2 keep r2's proven single-barrier ping-pong and fragment indexing.
__global__ __launch_bounds__(512, 2) void mlp64_k(
        const unsigned short* __restrict__ xln,  // (R, C) bf16 = LN2(x2)
        const float* __restrict__ x2,            // residual fp32
        const unsigned short* __restrict__ w1s,  // frag-swizzled (256 x 1024)
        const float* __restrict__ b1,
        const unsigned short* __restrict__ w2s,  // frag-swizzled (1024 x 256)
        const float* __restrict__ b2,
        float* __restrict__ out) {
    __shared__ char lds_raw[66560];
    char* xblob = lds_raw;                       // 32 kq x 1040 B (64 rows x 16 B + 16 pad)
    char* h1b0  = lds_raw + 33280;               // 16 kq x 1040 B
    char* h1b1  = lds_raw + 49920;               // 16 kq x 1040 B
    float* trans = (float*)lds_raw;              // epilogue alias: 64 x 260 f32 = 66,560 B

    int t = threadIdx.x;
    int lane = t & 63, wave = t >> 6;
    int quad = lane >> 4, l16 = lane & 15;
    int row0 = blockIdx.x * 64;

    // ---- stage xln tile (64 x 256 bf16) fragment-major via global_load_lds ----
    // chunk c (0..2047): kq = c>>6 (wave-uniform), row = c&63 (the lane).
    #pragma unroll
    for (int s = 0; s < 4; ++s) {
        int c = s * 512 + t;
        int kq = c >> 6;                         // wave-uniform: s*8 + wave
        const unsigned short* src = xln + (size_t)(row0 + (c & 63)) * CC + kq * 8;
        char* dst = xblob + kq * 1040;           // + lane*16 by hardware
        __builtin_amdgcn_global_load_lds(
            (const __attribute__((address_space(1))) void*)src,
            (__attribute__((address_space(3))) void*)dst, 16, 0, 0);
    }
    __builtin_amdgcn_s_waitcnt(0);
    __syncthreads();

    f32x4 acc2[2][4];
    #pragma unroll
    for (int a = 0; a < 2; ++a)
        #pragma unroll
        for (int b = 0; b < 4; ++b)
            acc2[a][b] = (f32x4){0.f, 0.f, 0.f, 0.f};

    auto s1c = [&](int hc, char* dst) {
        f32x4 a[4];
        #pragma unroll
        for (int qt = 0; qt < 4; ++qt) a[qt] = (f32x4){0.f, 0.f, 0.f, 0.f};
        #pragma unroll
        for (int kb = 0; kb < 8; ++kb) {
            bf16x8 w = *(const bf16x8*)(w1s + ((size_t)(kb * 4 + quad) * 1024 + hc * 128 + wave * 16 + l16) * 8);
            #pragma unroll
            for (int qt = 0; qt < 4; ++qt) {
                bf16x8 bf = *(const bf16x8*)(xblob + (kb * 4 + quad) * 1040 + (qt * 16 + l16) * 16);
                a[qt] = __builtin_amdgcn_mfma_f32_16x16x32_bf16(w, bf, a[qt], 0, 0, 0);
            }
        }
        int hl = wave * 16 + quad * 4;
        float4 bb = *(const float4*)(b1 + hc * 128 + hl);
        const float* bp = (const float*)&bb;
        #pragma unroll
        for (int qt = 0; qt < 4; ++qt) {
            unsigned long long pk = 0;
            #pragma unroll
            for (int r = 0; r < 4; ++r) {
                float val = gelu_f(a[qt][r] + bp[r]);
                pk |= ((unsigned long long)f2bf(val)) << (16 * r);
            }
            *(unsigned long long*)(dst + (hl >> 3) * 1040 + (qt * 16 + l16) * 16 + (hl & 7) * 2) = pk;
        }
    };

    auto s2c = [&](int hc, const char* src) {
        #pragma unroll
        for (int k2 = 0; k2 < 4; ++k2) {
            bf16x8 w[2];
            #pragma unroll
            for (int ct = 0; ct < 2; ++ct)
                w[ct] = *(const bf16x8*)(w2s + ((size_t)((hc * 4 + k2) * 4 + quad) * 256 + wave * 32 + ct * 16 + l16) * 8);
            #pragma unroll
            for (int qt = 0; qt < 4; ++qt) {
                bf16x8 bf = *(const bf16x8*)(src + (k2 * 4 + quad) * 1040 + (qt * 16 + l16) * 16);
                #pragma unroll
                for (int ct = 0; ct < 2; ++ct)
                    acc2[ct][qt] = __builtin_amdgcn_mfma_f32_16x16x32_bf16(w[ct], bf, acc2[ct][qt], 0, 0, 0);
            }
        }
    };

    s1c(0, h1b0);
    for (int hc = 0; hc < 8; ++hc) {
        __syncthreads();
        const char* cur = (hc & 1) ? h1b1 : h1b0;
        char*       nxt = (hc & 1) ? h1b0 : h1b1;
        s2c(hc, cur);
        if (hc < 7) s1c(hc + 1, nxt);
    }
    __syncthreads();

    // ---- epilogue: transpose via LDS (aliases xblob/h1b*), + x2 + b2, coalesced f32 ----
    #pragma unroll
    for (int qt = 0; qt < 4; ++qt) {
        int qrow = qt * 16 + l16;
        #pragma unroll
        for (int ct = 0; ct < 2; ++ct) {
            int c4 = wave * 8 + ct * 4 + quad;
            *(f32x4*)(trans + qrow * 260 + c4 * 4) = acc2[ct][qt];
        }
    }
    __syncthreads();
    {
        int rr = t >> 3, c8 = t & 7;             // 64 rows x 8 col-groups
        int row = row0 + rr;
        #pragma unroll
        for (int i = 0; i < 8; ++i) {
            int c4 = c8 + i * 8;
            int c = c4 * 4;
            f32x4 vv = *(const f32x4*)(trans + rr * 260 + c);
            float4 xv = *(const float4*)(x2 + (size_t)row * CC + c);
            float4 bb = *(const float4*)(b2 + c);
            float4 o;
            o.x = vv[0] + xv.x + bb.x;
            o.y = vv[1] + xv.y + bb.y;
            o.z = vv[2] + xv.z + bb.z;
            o.w = vv[3] + xv.w + bb.w;
            *(float4*)(out + (size_t)row * CC + c) = o;
        }
    }
}

extern "C" void kernel_launch(void* const* d_in, const int* in_sizes, int n_in,
                              void* d_out, int out_size, void* d_ws, size_t ws_size,
                              hipStream_t stream) {
    const float* x     = (const float*)d_in[0];
    const float* ref   = (const float*)d_in[1];
    const float* value = (const float*)d_in[2];
    const float* ln1w  = (const float*)d_in[5];
    const float* ln1b  = (const float*)d_in[6];
    const float* ln2w  = (const float*)d_in[7];
    const float* ln2b  = (const float*)d_in[8];
    const float* Wv    = (const float*)d_in[9];
    const float* bv    = (const float*)d_in[10];
    const float* Woff  = (const float*)d_in[11];
    const float* boff  = (const float*)d_in[12];
    const float* Wa    = (const float*)d_in[13];
    const float* ba    = (const float*)d_in[14];
    const float* Wout  = (const float*)d_in[15];
    const float* bout  = (const float*)d_in[16];
    const float* W1    = (const float*)d_in[17];
    const float* b1    = (const float*)d_in[18];
    const float* W2    = (const float*)d_in[19];
    const float* b2    = (const float*)d_in[20];

    // ---- workspace layout (bytes), total 58,720,768 ----
    // xln reuses the val_b slot (dead after the value-projection GEMM).
    char* ws = (char*)d_ws;
    unsigned short* wtv_b  = (unsigned short*)(ws + 0);          // 131072
    unsigned short* wouts_b= (unsigned short*)(ws + 131072);     // 131072
    unsigned short* w1s_b  = (unsigned short*)(ws + 262144);     // 524288
    unsigned short* w2s_b  = (unsigned short*)(ws + 786432);     // 524288
    unsigned short* woas_b = (unsigned short*)(ws + 1310720);    // 65536
    float*          b_oa   = (float*)         (ws + 1376256);    // 512
    float*          x2_f   = (float*)         (ws + 1376768);    // 26,214,400
    unsigned short* val_b  = (unsigned short*)(ws + 27591168);   // 13,107,200 (val | xln)
    unsigned short* v_b    = (unsigned short*)(ws + 40698368);   // 13,107,200
    unsigned short* oa_b   = (unsigned short*)(ws + 53805568);   // 4,915,200 -> 58,720,768

    // one-shot weight prep (transpose + fragment swizzles + bias concat)
    prep_k<<<561, 256, 0, stream>>>(Wv, Wout, W1, W2, Woff, Wa, boff, ba,
                                    wtv_b, wouts_b, w1s_b, w2s_b, woas_b, b_oa);
    // value fp32 -> bf16
    cvt_k<<<(RTOT*CC/4 + 255) / 256, 256, 0, stream>>>(value, val_b, RTOT*CC/4);
    // value projection -> v_b  (128x128-tile GEMM)
    gemm128<0, false><<<dim3(RTOT/128, 2), 256, 0, stream>>>(val_b, wtv_b, bv, nullptr, v_b, RTOT, 256, 256);
    // fused LN1 + offsets/logits -> oa_b
    lnoa_k<<<RTOT/64, 512, 0, stream>>>(x, ln1w, ln1b, woas_b, b_oa, oa_b);

    unsigned short* xln_b = val_b;   // val_b dead after value projection
    // fused sampling + Wout + residual -> x2, + LN2 -> xln
    samwout_k<<<RTOT/64, 512, 0, stream>>>(v_b, ref, oa_b, wouts_b, bout, x, x2_f,
                                           xln_b, ln2w, ln2b);
    // fused MLP (64-row blocks, h stays in LDS) -> out
    mlp64_k<<<RTOT/64, 512, 0, stream>>>(xln_b, x2_f, w1s_b, b1, w2s_b, b2, (float*)d_out);
}